// Round 6
// baseline (136.669 us; speedup 1.0000x reference)
//
#include <hip/hip_runtime.h>
#include <hip/hip_bf16.h>
#include <math.h>

#define NB      64      // batch
#define NNODES  1023    // 2*512-1
#define LC      20      // L*C = 5*4
#define DIN     512
#define NROWS   (NB * NNODES)   // 65472
#define ET_PAD  404     // 400 + 4 pad

#define TRW     128             // rows per gemm block
#define KC      32              // k per chunk
#define KP      36              // padded k stride (16B-aligned, bank-spread)
#define NCH     (DIN / KC)      // 16 chunks
#define SCP     21              // epilogue scratch stride

// ---------------------------------------------------------------------------
// prep: ET[q][i*20+j] = exp(trans[...]) reindexed; Wt[q][k] = W[k][q]
// ---------------------------------------------------------------------------
__global__ __launch_bounds__(256) void prep_kernel(
    const float* __restrict__ trans, const float* __restrict__ W,
    float* __restrict__ ET, float* __restrict__ Wt)
{
    int t = blockIdx.x * 256 + threadIdx.x;
    if (t < 8000) {
        int q   = t % 20;
        int rem = t / 20;
        int j   = rem % 20;
        int i   = rem / 20;
        int ll = i >> 2, cl = i & 3;
        int lr = j >> 2, cr = j & 3;
        int lp = q >> 2, cp = q & 3;
        int src = ((((lp * 5 + ll) * 5 + lr) * 4 + cp) * 4 + cl) * 4 + cr;
        ET[q * ET_PAD + i * 20 + j] = expf(trans[src]);
    }
    if (t < LC * DIN) {
        int q = t / DIN;
        int k = t - q * DIN;
        Wt[t] = W[k * LC + q];
    }
}

// ---------------------------------------------------------------------------
// gemm: buf[row][q] = dot(h[row,:], W[:,q]) + b[q]
// 4 waves/block q-split (5 q each); thread owns rows {lane, lane+64}.
// A: LDS double-buffer, 2-chunk-deep register prefetch (stays in flight
//    across barriers). W: wave-uniform global float4 loads (L1-resident,
//    VMEM pipe — keeps SMEM out of lgkmcnt and W out of LDS).
// ---------------------------------------------------------------------------
__global__ __launch_bounds__(256, 4) void gemm_kernel(
    const float* __restrict__ h, const float* __restrict__ Wt,
    const float* __restrict__ bias, float* __restrict__ buf)
{
    __shared__ float As[2][TRW][KP];   // 36,864 B -> 4 blocks/CU
    const int t    = threadIdx.x;
    const int lane = t & 63;
    const int wv   = t >> 6;
    const int w5   = __builtin_amdgcn_readfirstlane(wv * 5);
    const size_t row0 = (size_t)blockIdx.x * TRW;

    // 4 staging source pointers (row-clamped once); LDS slots fixed per thread
    const float* hp0; const float* hp1; const float* hp2; const float* hp3;
    {
        int s0 = t, s1 = t + 256, s2 = t + 512, s3 = t + 768;
        size_t g0 = row0 + (s0 >> 3); if (g0 >= NROWS) g0 = NROWS - 1;
        size_t g1 = row0 + (s1 >> 3); if (g1 >= NROWS) g1 = NROWS - 1;
        size_t g2 = row0 + (s2 >> 3); if (g2 >= NROWS) g2 = NROWS - 1;
        size_t g3 = row0 + (s3 >> 3); if (g3 >= NROWS) g3 = NROWS - 1;
        hp0 = h + g0 * DIN + (s0 & 7) * 4;
        hp1 = h + g1 * DIN + (s1 & 7) * 4;
        hp2 = h + g2 * DIN + (s2 & 7) * 4;
        hp3 = h + g3 * DIN + (s3 & 7) * 4;
    }
    float* ld0 = &As[0][(t      ) >> 3][((t      ) & 7) * 4];
    float* ld1 = &As[0][(t + 256) >> 3][((t + 256) & 7) * 4];
    float* ld2 = &As[0][(t + 512) >> 3][((t + 512) & 7) * 4];
    float* ld3 = &As[0][(t + 768) >> 3][((t + 768) & 7) * 4];
    const int bufStride = TRW * KP;    // floats between As[0] and As[1]

    float4 pfA0, pfA1, pfA2, pfA3, pfB0, pfB1, pfB2, pfB3;
    pfA0 = *(const float4*)(hp0);      pfA1 = *(const float4*)(hp1);
    pfA2 = *(const float4*)(hp2);      pfA3 = *(const float4*)(hp3);
    pfB0 = *(const float4*)(hp0 + KC); pfB1 = *(const float4*)(hp1 + KC);
    pfB2 = *(const float4*)(hp2 + KC); pfB3 = *(const float4*)(hp3 + KC);

    *(float4*)ld0 = pfA0; *(float4*)ld1 = pfA1;
    *(float4*)ld2 = pfA2; *(float4*)ld3 = pfA3;
    __syncthreads();

    float acc0[5] = {0.f,0.f,0.f,0.f,0.f};
    float acc1[5] = {0.f,0.f,0.f,0.f,0.f};
    const float4* wbase = (const float4*)(Wt + (size_t)w5 * DIN);

#define COMPUTE(P, CC)                                                       \
    {                                                                        \
        _Pragma("unroll")                                                    \
        for (int k4 = 0; k4 < 8; ++k4) {                                     \
            float4 a0 = *(const float4*)&As[P][lane     ][k4 * 4];           \
            float4 a1 = *(const float4*)&As[P][lane + 64][k4 * 4];           \
            const float4* wp = wbase + (CC) * 8 + k4;                        \
            _Pragma("unroll")                                                \
            for (int j = 0; j < 5; ++j) {                                    \
                float4 w = wp[j * (DIN / 4)];                                \
                acc0[j] = fmaf(a0.x, w.x, acc0[j]);                          \
                acc0[j] = fmaf(a0.y, w.y, acc0[j]);                          \
                acc0[j] = fmaf(a0.z, w.z, acc0[j]);                          \
                acc0[j] = fmaf(a0.w, w.w, acc0[j]);                          \
                acc1[j] = fmaf(a1.x, w.x, acc1[j]);                          \
                acc1[j] = fmaf(a1.y, w.y, acc1[j]);                          \
                acc1[j] = fmaf(a1.z, w.z, acc1[j]);                          \
                acc1[j] = fmaf(a1.w, w.w, acc1[j]);                          \
            }                                                                \
        }                                                                    \
    }

    for (int c = 0; c < NCH; c += 2) {
        // phase A: As[0] holds chunk c, pfB holds c+1; issue c+2 -> pfA
        if (c + 2 < NCH) {
            pfA0 = *(const float4*)(hp0 + (c + 2) * KC);
            pfA1 = *(const float4*)(hp1 + (c + 2) * KC);
            pfA2 = *(const float4*)(hp2 + (c + 2) * KC);
            pfA3 = *(const float4*)(hp3 + (c + 2) * KC);
        }
        COMPUTE(0, c)
        *(float4*)(ld0 + bufStride) = pfB0;
        *(float4*)(ld1 + bufStride) = pfB1;
        *(float4*)(ld2 + bufStride) = pfB2;
        *(float4*)(ld3 + bufStride) = pfB3;
        __syncthreads();

        // phase B: As[1] holds c+1, pfA holds c+2; issue c+3 -> pfB
        if (c + 3 < NCH) {
            pfB0 = *(const float4*)(hp0 + (c + 3) * KC);
            pfB1 = *(const float4*)(hp1 + (c + 3) * KC);
            pfB2 = *(const float4*)(hp2 + (c + 3) * KC);
            pfB3 = *(const float4*)(hp3 + (c + 3) * KC);
        }
        COMPUTE(1, c + 1)
        if (c + 2 < NCH) {
            *(float4*)ld0 = pfA0; *(float4*)ld1 = pfA1;
            *(float4*)ld2 = pfA2; *(float4*)ld3 = pfA3;
            __syncthreads();
        }
    }
#undef COMPUTE

    // epilogue: add bias, transpose via LDS scratch, coalesced float4 stores
    __syncthreads();
    float* sc = (float*)As;            // [128][SCP=21] reuse
    #pragma unroll
    for (int j = 0; j < 5; ++j) {
        float bj = bias[w5 + j];
        sc[(lane     ) * SCP + w5 + j] = acc0[j] + bj;
        sc[(lane + 64) * SCP + w5 + j] = acc1[j] + bj;
    }
    __syncthreads();
    {
        const size_t rem = NROWS - row0;
        const int vmax = (int)((rem < TRW ? rem : TRW) * 5);
        #pragma unroll
        for (int i = 0; i < 3; ++i) {
            int p = t + 256 * i;       // float4 index within block output
            if (p < 640 && p < vmax) {
                int f0 = p * 4;
                float4 o;
                o.x = sc[((f0+0)/20)*SCP + (f0+0)%20];
                o.y = sc[((f0+1)/20)*SCP + (f0+1)%20];
                o.z = sc[((f0+2)/20)*SCP + (f0+2)%20];
                o.w = sc[((f0+3)/20)*SCP + (f0+3)%20];
                ((float4*)(buf + row0 * LC))[p] = o;
            }
        }
    }
}

// ---------------------------------------------------------------------------
// level body (shared by level_kernel and tail_kernel)
// ---------------------------------------------------------------------------
__device__ __forceinline__ void level_body(
    float* __restrict__ buf, const float* __restrict__ et,
    float* __restrict__ out, int bi, int node, int q)
{
    size_t pbase = ((size_t)bi * NNODES + node) * LC;
    size_t lbase = ((size_t)bi * NNODES + 2 * node + 1) * LC;

    float l[LC], r[LC];
    const float4* l4 = (const float4*)(buf + lbase);
    const float4* r4 = (const float4*)(buf + lbase + LC);
    #pragma unroll
    for (int v = 0; v < 5; ++v) {
        float4 lv = l4[v], rv = r4[v];
        l[4*v+0] = lv.x; l[4*v+1] = lv.y; l[4*v+2] = lv.z; l[4*v+3] = lv.w;
        r[4*v+0] = rv.x; r[4*v+1] = rv.y; r[4*v+2] = rv.z; r[4*v+3] = rv.w;
    }
    float maxl = l[0], maxr = r[0];
    #pragma unroll
    for (int i = 1; i < LC; ++i) {
        maxl = fmaxf(maxl, l[i]);
        maxr = fmaxf(maxr, r[i]);
    }
    float el[LC], er[LC];
    #pragma unroll
    for (int i = 0; i < LC; ++i) {
        el[i] = __expf(l[i] - maxl);
        er[i] = __expf(r[i] - maxr);
    }

    const float4* etq = (const float4*)(et + q * ET_PAD);
    float s = 0.f;
    #pragma unroll
    for (int i = 0; i < LC; ++i) {
        float4 e0 = etq[i*5+0], e1 = etq[i*5+1], e2 = etq[i*5+2],
               e3 = etq[i*5+3], e4 = etq[i*5+4];
        float d0 = 0.f, d1 = 0.f;
        d0 = fmaf(e0.x, er[0],  d0); d1 = fmaf(e0.y, er[1],  d1);
        d0 = fmaf(e0.z, er[2],  d0); d1 = fmaf(e0.w, er[3],  d1);
        d0 = fmaf(e1.x, er[4],  d0); d1 = fmaf(e1.y, er[5],  d1);
        d0 = fmaf(e1.z, er[6],  d0); d1 = fmaf(e1.w, er[7],  d1);
        d0 = fmaf(e2.x, er[8],  d0); d1 = fmaf(e2.y, er[9],  d1);
        d0 = fmaf(e2.z, er[10], d0); d1 = fmaf(e2.w, er[11], d1);
        d0 = fmaf(e3.x, er[12], d0); d1 = fmaf(e3.y, er[13], d1);
        d0 = fmaf(e3.z, er[14], d0); d1 = fmaf(e3.w, er[15], d1);
        d0 = fmaf(e4.x, er[16], d0); d1 = fmaf(e4.y, er[17], d1);
        d0 = fmaf(e4.z, er[18], d0); d1 = fmaf(e4.w, er[19], d1);
        s = fmaf(el[i], d0 + d1, s);
    }

    float val = buf[pbase + q] + maxl + maxr + __logf(s);
    buf[pbase + q] = val;
    if (out) out[(size_t)bi * LC + q] = val;
}

// ---------------------------------------------------------------------------
// level: one launch per level for d = 8, 7, 6
// ---------------------------------------------------------------------------
__global__ __launch_bounds__(256) void level_kernel(
    float* __restrict__ buf, const float* __restrict__ ETg,
    int start, int count)
{
    __shared__ float et[LC * ET_PAD];
    for (int idx = threadIdx.x; idx < LC * ET_PAD / 4; idx += 256)
        ((float4*)et)[idx] = ((const float4*)ETg)[idx];
    __syncthreads();

    int t  = blockIdx.x * 256 + threadIdx.x;
    int pj = t / LC;
    int q  = t - pj * LC;
    if (pj >= NB * count) return;
    int bi   = pj / count;
    int node = start + (pj - bi * count);
    level_body(buf, et, nullptr, bi, node, q);
}

// ---------------------------------------------------------------------------
// tail: levels d = 5..0 fused, one block per batch element
// ---------------------------------------------------------------------------
__global__ __launch_bounds__(640) void tail_kernel(
    float* __restrict__ buf, const float* __restrict__ ETg,
    float* __restrict__ out)
{
    __shared__ float et[LC * ET_PAD];
    for (int idx = threadIdx.x; idx < LC * ET_PAD / 4; idx += 640)
        ((float4*)et)[idx] = ((const float4*)ETg)[idx];
    __syncthreads();

    const int bi = blockIdx.x;
    for (int d = 5; d >= 0; --d) {
        int count = 1 << d;
        int start = count - 1;
        int t = threadIdx.x;
        if (t < count * LC) {
            int node = start + t / LC;
            int q    = t % LC;
            level_body(buf, et, (d == 0) ? out : nullptr, bi, node, q);
        }
        __syncthreads();
    }
}

// ---------------------------------------------------------------------------
extern "C" void kernel_launch(void* const* d_in, const int* in_sizes, int n_in,
                              void* d_out, int out_size, void* d_ws, size_t ws_size,
                              hipStream_t stream)
{
    const float* h     = (const float*)d_in[0];
    const float* W     = (const float*)d_in[1];
    const float* bias  = (const float*)d_in[2];
    const float* trans = (const float*)d_in[3];

    char* ws = (char*)d_ws;
    float* ET  = (float*)(ws);                       // 32320 B (pad to 32768)
    float* Wt  = (float*)(ws + 32768);               // 20*512*4 = 40960 B
    float* buf = (float*)(ws + 32768 + 40960);       // 65472*20*4 B

    // 1. precompute exp(trans) reindexed + W^T
    prep_kernel<<<(LC * DIN + 255) / 256, 256, 0, stream>>>(trans, W, ET, Wt);

    // 2. sw = h@W + b   (512 blocks, 4 blocks/CU target)
    gemm_kernel<<<(NROWS + TRW - 1) / TRW, 256, 0, stream>>>(h, Wt, bias, buf);

    // 3. inside pass: big levels separate, small levels fused
    for (int d = 8; d >= 6; --d) {
        int count = 1 << d;
        int start = count - 1;
        int T = NB * count * LC;
        level_kernel<<<(T + 255) / 256, 256, 0, stream>>>(buf, ET, start, count);
    }
    tail_kernel<<<NB, 640, 0, stream>>>(buf, ET, (float*)d_out);
}

// Round 7
// 71.234 us; speedup vs baseline: 1.9186x; 1.9186x over previous
//
#include <hip/hip_runtime.h>
#include <hip/hip_bf16.h>
#include <math.h>

#define NB      64      // batch
#define NNODES  1023    // 2*512-1
#define LC      20      // L*C = 5*4
#define DIN     512
#define NROWS   (NB * NNODES)   // 65472
#define ET_PAD  404     // 400 + 4 pad

#define BM      128             // rows per gemm block
#define BK      64              // f32 k per chunk
#define NKC     (DIN / BK)      // 8 chunks
#define SCP     21              // epilogue scratch stride

typedef unsigned short u16;
typedef short bf16x8 __attribute__((ext_vector_type(8)));
typedef float f32x4  __attribute__((ext_vector_type(4)));

__device__ __forceinline__ u16 f2bf(float f) {   // RNE f32 -> bf16 bits
    unsigned x = __float_as_uint(f);
    return (u16)((x + 0x7FFFu + ((x >> 16) & 1u)) >> 16);
}

// ---------------------------------------------------------------------------
// prep: ET (exp(trans) reindexed) + B fragments in MFMA per-lane layout.
// Bfrag[(ks*2+nf)*64 + lane] (uint4 = 8 bf16): lane holds
//   W[ks*32 + (lane>>4)*8 + j][nf*16 + (lane&15)], cols >= 20 zeroed.
// (A-side uses the same K-slot permutation, so any internal K map cancels.)
// ---------------------------------------------------------------------------
__global__ __launch_bounds__(256) void prep_kernel(
    const float* __restrict__ trans, const float* __restrict__ W,
    float* __restrict__ ET, u16* __restrict__ Bfrag)
{
    int t = blockIdx.x * 256 + threadIdx.x;
    if (t < 8000) {
        int q   = t % 20;
        int rem = t / 20;
        int j   = rem % 20;
        int i   = rem / 20;
        int ll = i >> 2, cl = i & 3;
        int lr = j >> 2, cr = j & 3;
        int lp = q >> 2, cp = q & 3;
        int src = ((((lp * 5 + ll) * 5 + lr) * 4 + cp) * 4 + cl) * 4 + cr;
        ET[q * ET_PAD + i * 20 + j] = expf(trans[src]);
    }
    if (t < 2048) {
        int lane = t & 63, nf = (t >> 6) & 1, ks = t >> 7;
        int col = nf * 16 + (lane & 15);
        int kb  = ks * 32 + (lane >> 4) * 8;
        unsigned e[8];
        #pragma unroll
        for (int j = 0; j < 8; ++j)
            e[j] = (col < LC) ? (unsigned)f2bf(W[(kb + j) * LC + col]) : 0u;
        uint4 v;
        v.x = e[0] | (e[1] << 16); v.y = e[2] | (e[3] << 16);
        v.z = e[4] | (e[5] << 16); v.w = e[6] | (e[7] << 16);
        ((uint4*)Bfrag)[t] = v;
    }
}

// ---------------------------------------------------------------------------
// gemm via mfma_f32_16x16x32_bf16. 4 waves; wave wv owns rows [wv*32,wv*32+32).
// A: f32 global -> RNE cvt -> swizzled bf16 LDS (dbuf), 3-deep reg prefetch.
// B: fragment array copied to LDS once. D-map: col=lane&15, row=(lane>>4)*4+p.
// ---------------------------------------------------------------------------
__global__ __launch_bounds__(256, 2) void gemm_kernel(
    const float* __restrict__ h, const u16* __restrict__ Bfrag,
    const float* __restrict__ bias, float* __restrict__ buf)
{
    __shared__ u16 AsU[2][BM][64];     // 32 KB swizzled bf16 A tiles
    __shared__ u16 BsU[2048 * 8];      // 32 KB B fragments
    const int t    = threadIdx.x;
    const int lane = t & 63;
    const int wv   = t >> 6;
    const size_t row0 = (size_t)blockIdx.x * BM;

    // B fragments -> LDS (2048 uint4, coalesced)
    {
        const uint4* s = (const uint4*)Bfrag;
        uint4* d = (uint4*)BsU;
        #pragma unroll
        for (int i = 0; i < 8; ++i) d[t + 256 * i] = s[t + 256 * i];
    }

    // staging geometry: thread covers rows srow+16i (i=0..7), f32-quad sk4
    const int srow = t >> 4;           // 0..15
    const int sk4  = t & 15;           // 0..15 (64 f32 per row)
    const int woff = (((sk4 >> 1) ^ (srow & 7)) << 3) + ((sk4 & 1) << 2); // u16s
    const float* hp[8];
    #pragma unroll
    for (int i = 0; i < 8; ++i) {
        size_t gr = row0 + srow + 16 * i;
        if (gr >= NROWS) gr = NROWS - 1;
        hp[i] = h + gr * DIN + sk4 * 4;
    }

    f32x4 acc00 = {0.f,0.f,0.f,0.f}, acc01 = {0.f,0.f,0.f,0.f};
    f32x4 acc10 = {0.f,0.f,0.f,0.f}, acc11 = {0.f,0.f,0.f,0.f};
    float4 R0[8], R1[8], R2[8];

#define ISSUE(RB, CC) { _Pragma("unroll")                                     \
    for (int i = 0; i < 8; ++i) RB[i] = *(const float4*)(hp[i] + (CC) * BK); }

#define CVTWRITE(RB, P) { u16* _b = &AsU[P][0][0] + woff; _Pragma("unroll")   \
    for (int i = 0; i < 8; ++i) {                                             \
        uint2 pk;                                                             \
        pk.x = (unsigned)f2bf(RB[i].x) | ((unsigned)f2bf(RB[i].y) << 16);     \
        pk.y = (unsigned)f2bf(RB[i].z) | ((unsigned)f2bf(RB[i].w) << 16);     \
        *(uint2*)(_b + (srow + 16 * i) * 64) = pk; } }

#define COMPUTE(P, C) { const u16* _ab = &AsU[P][0][0]; _Pragma("unroll")     \
    for (int kc = 0; kc < 2; ++kc) {                                          \
        int rsl = (((kc * 4 + (lane >> 4)) ^ (lane & 7)) << 3);               \
        bf16x8 a0 = *(const bf16x8*)(_ab + (wv*32      + (lane&15))*64 + rsl);\
        bf16x8 a1 = *(const bf16x8*)(_ab + (wv*32 + 16 + (lane&15))*64 + rsl);\
        const u16* _bb = &BsU[(((C)*2 + kc) * 2 * 64 + lane) * 8];            \
        bf16x8 b0 = *(const bf16x8*)(_bb);                                    \
        bf16x8 b1 = *(const bf16x8*)(_bb + 64 * 8);                           \
        acc00 = __builtin_amdgcn_mfma_f32_16x16x32_bf16(a0, b0, acc00, 0,0,0);\
        acc01 = __builtin_amdgcn_mfma_f32_16x16x32_bf16(a0, b1, acc01, 0,0,0);\
        acc10 = __builtin_amdgcn_mfma_f32_16x16x32_bf16(a1, b0, acc10, 0,0,0);\
        acc11 = __builtin_amdgcn_mfma_f32_16x16x32_bf16(a1, b1, acc11, 0,0,0);\
    } }

    // prologue: 3 chunks issued, chunk0 staged
    ISSUE(R0, 0); ISSUE(R1, 1); ISSUE(R2, 2);
    CVTWRITE(R0, 0);
    __syncthreads();

    #pragma unroll
    for (int c = 0; c < NKC; ++c) {
        if (c + 3 < NKC) {              // reuse bank holding consumed chunk c
            if ((c % 3) == 0)      { ISSUE(R0, c + 3); }
            else if ((c % 3) == 1) { ISSUE(R1, c + 3); }
            else                   { ISSUE(R2, c + 3); }
        }
        COMPUTE(c & 1, c);
        if (c + 1 < NKC) {              // stage chunk c+1 into other buffer
            if (((c + 1) % 3) == 0)      { CVTWRITE(R0, (c + 1) & 1); }
            else if (((c + 1) % 3) == 1) { CVTWRITE(R1, (c + 1) & 1); }
            else                         { CVTWRITE(R2, (c + 1) & 1); }
        }
        __syncthreads();
    }
#undef ISSUE
#undef CVTWRITE
#undef COMPUTE

    // epilogue: acc -> LDS scratch (over AsU[0]) -> coalesced float4 stores
    float* sc = (float*)&AsU[0][0][0];   // 128*21*4 = 10.75 KB
    #pragma unroll
    for (int mf = 0; mf < 2; ++mf) {
        #pragma unroll
        for (int nf = 0; nf < 2; ++nf) {
            f32x4 a = (mf == 0) ? (nf == 0 ? acc00 : acc01)
                                : (nf == 0 ? acc10 : acc11);
            int col = nf * 16 + (lane & 15);
            if (col < LC) {
                float bv = bias[col];
                #pragma unroll
                for (int p = 0; p < 4; ++p) {
                    int rl = wv * 32 + mf * 16 + (lane >> 4) * 4 + p;
                    sc[rl * SCP + col] = a[p] + bv;
                }
            }
        }
    }
    __syncthreads();
    {
        const size_t rem = NROWS - row0;
        const int vmax = (int)((rem < BM ? rem : (size_t)BM) * 5);
        #pragma unroll
        for (int i = 0; i < 3; ++i) {
            int p = t + 256 * i;
            if (p < 640 && p < vmax) {
                int f0 = p * 4;
                float4 o;
                o.x = sc[((f0 + 0) / 20) * SCP + (f0 + 0) % 20];
                o.y = sc[((f0 + 1) / 20) * SCP + (f0 + 1) % 20];
                o.z = sc[((f0 + 2) / 20) * SCP + (f0 + 2) % 20];
                o.w = sc[((f0 + 3) / 20) * SCP + (f0 + 3) % 20];
                ((float4*)(buf + row0 * LC))[p] = o;
            }
        }
    }
}

// ---------------------------------------------------------------------------
// level body (shared by level_kernel and tail_kernel)
// ---------------------------------------------------------------------------
__device__ __forceinline__ void level_body(
    float* __restrict__ buf, const float* __restrict__ et,
    float* __restrict__ out, int bi, int node, int q)
{
    size_t pbase = ((size_t)bi * NNODES + node) * LC;
    size_t lbase = ((size_t)bi * NNODES + 2 * node + 1) * LC;

    float l[LC], r[LC];
    const float4* l4 = (const float4*)(buf + lbase);
    const float4* r4 = (const float4*)(buf + lbase + LC);
    #pragma unroll
    for (int v = 0; v < 5; ++v) {
        float4 lv = l4[v], rv = r4[v];
        l[4*v+0] = lv.x; l[4*v+1] = lv.y; l[4*v+2] = lv.z; l[4*v+3] = lv.w;
        r[4*v+0] = rv.x; r[4*v+1] = rv.y; r[4*v+2] = rv.z; r[4*v+3] = rv.w;
    }
    float maxl = l[0], maxr = r[0];
    #pragma unroll
    for (int i = 1; i < LC; ++i) {
        maxl = fmaxf(maxl, l[i]);
        maxr = fmaxf(maxr, r[i]);
    }
    float el[LC], er[LC];
    #pragma unroll
    for (int i = 0; i < LC; ++i) {
        el[i] = __expf(l[i] - maxl);
        er[i] = __expf(r[i] - maxr);
    }

    const float4* etq = (const float4*)(et + q * ET_PAD);
    float s = 0.f;
    #pragma unroll
    for (int i = 0; i < LC; ++i) {
        float4 e0 = etq[i*5+0], e1 = etq[i*5+1], e2 = etq[i*5+2],
               e3 = etq[i*5+3], e4 = etq[i*5+4];
        float d0 = 0.f, d1 = 0.f;
        d0 = fmaf(e0.x, er[0],  d0); d1 = fmaf(e0.y, er[1],  d1);
        d0 = fmaf(e0.z, er[2],  d0); d1 = fmaf(e0.w, er[3],  d1);
        d0 = fmaf(e1.x, er[4],  d0); d1 = fmaf(e1.y, er[5],  d1);
        d0 = fmaf(e1.z, er[6],  d0); d1 = fmaf(e1.w, er[7],  d1);
        d0 = fmaf(e2.x, er[8],  d0); d1 = fmaf(e2.y, er[9],  d1);
        d0 = fmaf(e2.z, er[10], d0); d1 = fmaf(e2.w, er[11], d1);
        d0 = fmaf(e3.x, er[12], d0); d1 = fmaf(e3.y, er[13], d1);
        d0 = fmaf(e3.z, er[14], d0); d1 = fmaf(e3.w, er[15], d1);
        d0 = fmaf(e4.x, er[16], d0); d1 = fmaf(e4.y, er[17], d1);
        d0 = fmaf(e4.z, er[18], d0); d1 = fmaf(e4.w, er[19], d1);
        s = fmaf(el[i], d0 + d1, s);
    }

    float val = buf[pbase + q] + maxl + maxr + __logf(s);
    buf[pbase + q] = val;
    if (out) out[(size_t)bi * LC + q] = val;
}

// ---------------------------------------------------------------------------
// level: one launch per level for d = 8, 7, 6
// ---------------------------------------------------------------------------
__global__ __launch_bounds__(256) void level_kernel(
    float* __restrict__ buf, const float* __restrict__ ETg,
    int start, int count)
{
    __shared__ float et[LC * ET_PAD];
    for (int idx = threadIdx.x; idx < LC * ET_PAD / 4; idx += 256)
        ((float4*)et)[idx] = ((const float4*)ETg)[idx];
    __syncthreads();

    int t  = blockIdx.x * 256 + threadIdx.x;
    int pj = t / LC;
    int q  = t - pj * LC;
    if (pj >= NB * count) return;
    int bi   = pj / count;
    int node = start + (pj - bi * count);
    level_body(buf, et, nullptr, bi, node, q);
}

// ---------------------------------------------------------------------------
// tail: levels d = 5..0 fused, one block per batch element
// ---------------------------------------------------------------------------
__global__ __launch_bounds__(640) void tail_kernel(
    float* __restrict__ buf, const float* __restrict__ ETg,
    float* __restrict__ out)
{
    __shared__ float et[LC * ET_PAD];
    for (int idx = threadIdx.x; idx < LC * ET_PAD / 4; idx += 640)
        ((float4*)et)[idx] = ((const float4*)ETg)[idx];
    __syncthreads();

    const int bi = blockIdx.x;
    for (int d = 5; d >= 0; --d) {
        int count = 1 << d;
        int start = count - 1;
        int t = threadIdx.x;
        if (t < count * LC) {
            int node = start + t / LC;
            int q    = t % LC;
            level_body(buf, et, (d == 0) ? out : nullptr, bi, node, q);
        }
        __syncthreads();
    }
}

// ---------------------------------------------------------------------------
extern "C" void kernel_launch(void* const* d_in, const int* in_sizes, int n_in,
                              void* d_out, int out_size, void* d_ws, size_t ws_size,
                              hipStream_t stream)
{
    const float* h     = (const float*)d_in[0];
    const float* W     = (const float*)d_in[1];
    const float* bias  = (const float*)d_in[2];
    const float* trans = (const float*)d_in[3];

    char* ws = (char*)d_ws;
    float* ET    = (float*)(ws);                     // 32320 B (pad to 32768)
    u16*   Bfrag = (u16*)(ws + 32768);               // 32768 B
    float* buf   = (float*)(ws + 65536);             // 65472*20*4 B

    // 1. precompute exp(trans) reindexed + B fragments
    prep_kernel<<<32, 256, 0, stream>>>(trans, W, ET, Bfrag);

    // 2. sw = h@W + b  (MFMA bf16, 512 blocks)
    gemm_kernel<<<(NROWS + BM - 1) / BM, 256, 0, stream>>>(h, Bfrag, bias, buf);

    // 3. inside pass: big levels separate, small levels fused
    for (int d = 8; d >= 6; --d) {
        int count = 1 << d;
        int start = count - 1;
        int T = NB * count * LC;
        level_kernel<<<(T + 255) / 256, 256, 0, stream>>>(buf, ET, start, count);
    }
    tail_kernel<<<NB, 640, 0, stream>>>(buf, ET, (float*)d_out);
}